// Round 1
// 82.201 us; speedup vs baseline: 1.0891x; 1.0891x over previous
//
#include <hip/hip_runtime.h>
#include <hip/hip_fp16.h>
#include <cstdint>
#include <cstddef>

#define BATCH 8
#define NPTS  2048
#define CH1   64
#define CH2   128
#define NSAMP 64

typedef _Float16 half8v  __attribute__((ext_vector_type(8)));
typedef _Float16 half2v  __attribute__((ext_vector_type(2)));
typedef float    float4v __attribute__((ext_vector_type(4)));
typedef unsigned uint4v  __attribute__((ext_vector_type(4)));

// packed f16 max, compiler-visible (lowers to v_pk_max_f16)
__device__ inline unsigned pmax(unsigned a, unsigned b) {
  half2v ha = __builtin_bit_cast(half2v, a);
  half2v hb = __builtin_bit_cast(half2v, b);
  return __builtin_bit_cast(unsigned, __builtin_elementwise_max(ha, hb));
}

__device__ inline uint4v pk4max(uint4v a, uint4v b) {
  uint4v d;
#pragma unroll
  for (int i = 0; i < 4; ++i) d[i] = pmax(a[i], b[i]);
  return d;
}

__device__ inline float h2lo(unsigned u) {
  return (float)__builtin_bit_cast(half2v, u)[0];
}
__device__ inline float h2hi(unsigned u) {
  return (float)__builtin_bit_cast(half2v, u)[1];
}

// ---------------------------------------------------------------------------
// Kernel 1: per-point MLP via MFMA (128 x 16384 x 64 fp16 GEMM). Unchanged
// (measured fast). Also emits xyzq[pt] = {x,y,z,|p|^2}.
// ---------------------------------------------------------------------------
__global__ __launch_bounds__(256) void mlp_kernel(
    const float* __restrict__ x,
    const float* __restrict__ W1, const float* __restrict__ b1,
    const float* __restrict__ W2, const float* __restrict__ b2,
    __half* __restrict__ h2, float4v* __restrict__ xyzq) {
  const int t = threadIdx.x;
  const int wave = t >> 6;
  const int lane = t & 63;
  const int n = lane & 15;
  const int quad = lane >> 4;
  const int pti = wave >> 1;
  const int mh  = wave & 1;
  const int base = blockIdx.x * 32;

  if (t < 32) {
    const int pt = base + t;
    const float X = x[pt * 3 + 0];
    const float Y = x[pt * 3 + 1];
    const float Z = x[pt * 3 + 2];
    float4v v;
    v[0] = X; v[1] = Y; v[2] = Z; v[3] = fmaf(Z, Z, fmaf(Y, Y, X * X));
    xyzq[pt] = v;
  }

  float w1x[16], w1y[16], w1z[16], b1v[16];
#pragma unroll
  for (int j = 0; j < 16; ++j) {
    const int o = quad * 8 + (j & 7) + ((j < 8) ? 0 : 32);
    w1x[j] = W1[o * 3 + 0];
    w1y[j] = W1[o * 3 + 1];
    w1z[j] = W1[o * 3 + 2];
    b1v[j] = b1[o];
  }

  half8v afrag[4][2];
  float4v bias[4];
#pragma unroll
  for (int mt = 0; mt < 4; ++mt) {
    const int mtg = mh * 4 + mt;
    const int m = mtg * 16 + n;
#pragma unroll
    for (int kf = 0; kf < 2; ++kf) {
      const float4v* wp = (const float4v*)(W2 + m * CH1 + kf * 32 + quad * 8);
      const float4v lo = wp[0];
      const float4v hi = wp[1];
#pragma unroll
      for (int e = 0; e < 4; ++e) {
        afrag[mt][kf][e]     = (_Float16)lo[e];
        afrag[mt][kf][4 + e] = (_Float16)hi[e];
      }
    }
    bias[mt] = *(const float4v*)(b2 + mtg * 16 + quad * 4);
  }

  const int pt = base + pti * 16 + n;
  const float X = x[pt * 3 + 0];
  const float Y = x[pt * 3 + 1];
  const float Z = x[pt * 3 + 2];
  half8v bf0, bf1;
#pragma unroll
  for (int j = 0; j < 8; ++j) {
    const float ha = fmaxf(fmaf(w1z[j], Z, fmaf(w1y[j], Y, fmaf(w1x[j], X, b1v[j]))), 0.f);
    const float hb = fmaxf(fmaf(w1z[8 + j], Z, fmaf(w1y[8 + j], Y, fmaf(w1x[8 + j], X, b1v[8 + j]))), 0.f);
    bf0[j] = (_Float16)ha;
    bf1[j] = (_Float16)hb;
  }

  __half* hrow = h2 + (size_t)pt * CH2;
#pragma unroll
  for (int mt = 0; mt < 4; ++mt) {
    const int mtg = mh * 4 + mt;
    float4v acc = bias[mt];
    acc = __builtin_amdgcn_mfma_f32_16x16x32_f16(afrag[mt][0], bf0, acc, 0, 0, 0);
    acc = __builtin_amdgcn_mfma_f32_16x16x32_f16(afrag[mt][1], bf1, acc, 0, 0, 0);
    const int p0 = mtg * 16 + quad * 4;
    half2v lo2, hi2;
    lo2[0] = (_Float16)fmaxf(acc[0], 0.f);
    lo2[1] = (_Float16)fmaxf(acc[1], 0.f);
    hi2[0] = (_Float16)fmaxf(acc[2], 0.f);
    hi2[1] = (_Float16)fmaxf(acc[3], 0.f);
    uint2 pk;
    pk.x = __builtin_bit_cast(unsigned, lo2);
    pk.y = __builtin_bit_cast(unsigned, hi2);
    *(uint2*)(hrow + p0) = pk;
  }
}

// ---------------------------------------------------------------------------
// Kernel 2 (R13): ONE WAVE PER QUERY, 4 queries (consecutive s) per block.
//  - phase 1 is wave-synchronous: ballot prefix, per-wave LDS list, ZERO
//    __syncthreads (old structure had ~6 full-block barriers on the
//    critical path of each of 16384 blocks).
//  - phase 2: each lane gathers its query's 16-B channel slice for 16 rows
//    (16x dwordx4), reduces in-register (15 pk4max) + 8 shfl_xor; the 4 KB
//    'partial' LDS round-trip and its 2 barriers are gone.
//  - epilogue: 4 waves transpose via 2 KB LDS (single __syncthreads) and
//    write out as float4 per channel line: 16-B line-touches instead of
//    4x scattered dwords (4x fewer L2 write transactions).
//  - XCD swizzle kept: b = bid&7 == XCD id -> xyzq L1-resident, h2 slice
//    L2-resident, out lines written by one XCD only.
// ---------------------------------------------------------------------------
__global__ __launch_bounds__(256, 4) void query_kernel(
    const float4v* __restrict__ xyzq,
    const __half* __restrict__ h2,
    float* __restrict__ out) {
  __shared__ int  list[4][NSAMP];   // 1 KB, per-wave private
  __shared__ float fout[4][CH2];    // 2 KB, 4-query output transpose

  const int t = threadIdx.x;
  const int wave = t >> 6;
  const int lane = t & 63;
  const int bid = blockIdx.x;
  const int b = bid & 7;                  // XCD id, owns batch b
  const int sbase = (bid >> 3) << 2;      // 4 consecutive queries
  const int s = sbase + wave;

  const float4v* xq = xyzq + (size_t)b * NPTS;
  const float4v qv = xq[s];
  const float qx = qv[0], qy = qv[1], qz = qv[2], dqf = qv[3];
  const double dq = (double)qx * qx + (double)qy * qy + (double)qz * qz;
  const unsigned long long lt = (1ull << lane) - 1ull;

  // ---- Phase 1: first NSAMP in-radius hits (ascending index), 128/iter,
  //      wave-synchronous (no barriers) ----
  int count = 0;
  int first = 0;
  for (int base = 0; base < NPTS && count < NSAMP; base += 128) {
    const float4v pv0 = xq[base + lane];
    const float4v pv1 = xq[base + 64 + lane];

    const float px0 = pv0[0], py0 = pv0[1], pz0 = pv0[2];
    const float dot0 = fmaf(qz, pz0, fmaf(qy, py0, qx * px0));
    const float dist0 = fmaf(-2.f, dot0, dqf + pv0[3]);
    bool hit0;
    if (__ballot(__builtin_fabsf(dist0 - 0.36f) <= 3e-5f)) {
      // rare exact path: fp64, same evaluation as the np reference
      const double dm = (double)px0 * px0 + (double)py0 * py0 + (double)pz0 * pz0;
      const double dd = (double)qx * px0 + (double)qy * py0 + (double)qz * pz0;
      hit0 = !((dq + dm - 2.0 * dd) > 0.36);
    } else {
      hit0 = !(dist0 > 0.36f);
    }

    const float px1 = pv1[0], py1 = pv1[1], pz1 = pv1[2];
    const float dot1 = fmaf(qz, pz1, fmaf(qy, py1, qx * px1));
    const float dist1 = fmaf(-2.f, dot1, dqf + pv1[3]);
    bool hit1;
    if (__ballot(__builtin_fabsf(dist1 - 0.36f) <= 3e-5f)) {
      const double dm = (double)px1 * px1 + (double)py1 * py1 + (double)pz1 * pz1;
      const double dd = (double)qx * px1 + (double)qy * py1 + (double)qz * pz1;
      hit1 = !((dq + dm - 2.0 * dd) > 0.36);
    } else {
      hit1 = !(dist1 > 0.36f);
    }

    const unsigned long long m0 = __ballot(hit0);
    const unsigned long long m1 = __ballot(hit1);
    const int c0 = __popcll(m0);
    const int c1 = __popcll(m1);

    if (count == 0) {
      first = m0 ? (base + (int)__builtin_ctzll(m0))
                 : (m1 ? (base + 64 + (int)__builtin_ctzll(m1)) : first);
    }
    if (hit0) {
      const int pos = count + __popcll(m0 & lt);
      if (pos < NSAMP) list[wave][pos] = base + lane;
    }
    if (hit1) {
      const int pos = count + c0 + __popcll(m1 & lt);
      if (pos < NSAMP) list[wave][pos] = base + 64 + lane;
    }
    count += c0 + c1;
  }
  // tail fill with first hit (self guarantees count >= 1 on full scan)
  if (count < NSAMP && lane >= count) list[wave][lane] = first;

  __builtin_amdgcn_wave_barrier();
  asm volatile("s_waitcnt lgkmcnt(0)" ::: "memory");
  __builtin_amdgcn_wave_barrier();

  // ---- Phase 2: lane = (rgrp, csl); gather rows rgrp*16..+15, 16-B slice
  //      csl; in-register max tree, then 2 shfl_xor rounds ----
  const int csl  = lane & 15;
  const int rgrp = lane >> 4;
  const __half* hb = h2 + (size_t)b * NPTS * CH2;

  unsigned off[16];
#pragma unroll
  for (int k = 0; k < 4; ++k) {
    const int4 li = *(const int4*)&list[wave][rgrp * 16 + k * 4];
    off[4 * k + 0] = (unsigned)(li.x * 256 + csl * 16);
    off[4 * k + 1] = (unsigned)(li.y * 256 + csl * 16);
    off[4 * k + 2] = (unsigned)(li.z * 256 + csl * 16);
    off[4 * k + 3] = (unsigned)(li.w * 256 + csl * 16);
  }

  uint4v acc;
  {
    uint4v v[8];
#pragma unroll
    for (int k = 0; k < 8; ++k)
      v[k] = *(const uint4v*)((const char*)hb + (size_t)off[k]);
    uint4v a0 = pk4max(pk4max(v[0], v[1]), pk4max(v[2], v[3]));
    uint4v a1 = pk4max(pk4max(v[4], v[5]), pk4max(v[6], v[7]));
    acc = pk4max(a0, a1);
  }
  {
    uint4v v[8];
#pragma unroll
    for (int k = 0; k < 8; ++k)
      v[k] = *(const uint4v*)((const char*)hb + (size_t)off[8 + k]);
    uint4v a0 = pk4max(pk4max(v[0], v[1]), pk4max(v[2], v[3]));
    uint4v a1 = pk4max(pk4max(v[4], v[5]), pk4max(v[6], v[7]));
    acc = pk4max(acc, pk4max(a0, a1));
  }

  // cross-lane: combine the 4 row-groups (lanes csl, csl+16, csl+32, csl+48)
  uint4v o;
#pragma unroll
  for (int i = 0; i < 4; ++i)
    o[i] = (unsigned)__shfl_xor((int)acc[i], 16, 64);
  acc = pk4max(acc, o);
#pragma unroll
  for (int i = 0; i < 4; ++i)
    o[i] = (unsigned)__shfl_xor((int)acc[i], 32, 64);
  acc = pk4max(acc, o);

  // lanes 0..15 hold the final 8-channel slice for this query
  if (rgrp == 0) {
    const int c0 = csl * 8;
    fout[wave][c0 + 0] = h2lo(acc[0]);
    fout[wave][c0 + 1] = h2hi(acc[0]);
    fout[wave][c0 + 2] = h2lo(acc[1]);
    fout[wave][c0 + 3] = h2hi(acc[1]);
    fout[wave][c0 + 4] = h2lo(acc[2]);
    fout[wave][c0 + 5] = h2hi(acc[2]);
    fout[wave][c0 + 6] = h2lo(acc[3]);
    fout[wave][c0 + 7] = h2hi(acc[3]);
  }
  __syncthreads();

  // ---- Epilogue: coalesced float4 write per channel line ----
  if (t < CH2) {
    float4v r;
    r[0] = fout[0][t];
    r[1] = fout[1][t];
    r[2] = fout[2][t];
    r[3] = fout[3][t];
    *(float4v*)(out + ((size_t)b * CH2 + t) * NPTS + sbase) = r;
  }
}

// ---------------------------------------------------------------------------
extern "C" void kernel_launch(void* const* d_in, const int* in_sizes, int n_in,
                              void* d_out, int out_size, void* d_ws, size_t ws_size,
                              hipStream_t stream) {
  const float* x  = (const float*)d_in[0];
  const float* W1 = (const float*)d_in[1];
  const float* b1 = (const float*)d_in[2];
  const float* W2 = (const float*)d_in[3];
  const float* b2 = (const float*)d_in[4];
  float* out = (float*)d_out;

  __half*  h2   = (__half*)d_ws;                                     // 4 MB
  float4v* xyzq = (float4v*)((char*)d_ws + (size_t)4 * 1024 * 1024); // 256 KB

  mlp_kernel<<<(BATCH * NPTS) / 32, 256, 0, stream>>>(
      x, W1, b1, W2, b2, h2, xyzq);
  query_kernel<<<(BATCH * NPTS) / 4, 256, 0, stream>>>(xyzq, h2, out);
}